// Round 11
// baseline (59.760 us; speedup 1.0000x reference)
//
#include <hip/hip_runtime.h>

// Butterfly (untied, increasing stride): BATCH=16384, N=1024, M=10, NSTACK=1.
// out = butterfly_mult(twiddle, x) + bias, all float32.
//
// Layout: pos = e_hi*256 + lane*4 + e_lo  (e_hi, e_lo in 0..3).
//   - stages 0..1: in-register pairs over e_lo bits.
//   - stages 2..7: cross-lane __shfl_xor over lane bits.
//   - stages 8..9: in-register pairs over e_hi bits.
//
// v11 = v5 structure (global repacked twiddle on the TA pipe -- proven 43us;
//     LDS-twiddle variants v9/v10 were SLOWER because twiddle reads joined
//     the shuffles on the saturated DS pipe) + pre-baked operand swap:
//     for stages 2..7 the repack kernel stores (a,b) = i==0 ? (t00,t01)
//                                                         : (t11,t10)
//     per lane, so the main loop is out = a*own + b*partner -- no cndmask.
//     5 -> 3 VALU-class ops per shuffled element (shfl+mul+fma), removing
//     ~384 instr/wave from the 6 hottest stages.
//     No launch_bounds min-waves (spill lesson v4/v6/v7/v8), no sweep loop
//     (LICM lesson v8), RPW=2 (RPW=4 needs ~140 VGPR).
//     Spill canary: WRITE_SIZE must be ~65536 KB.

#define BATCH 16384
#define NCOL 1024
#define RPW 2
#define TWS_BYTES (10 * 8 * 64 * 16)  // 81920

// ---------------- repack kernel: blockIdx.x = stage, threadIdx.x = lane ----
__global__ __launch_bounds__(64) void repack_tw(
    const float* __restrict__ tw, float4* __restrict__ ws)
{
    const int s = blockIdx.x;
    const int lane = threadIdx.x;
    const float4* raw4 = reinterpret_cast<const float4*>(tw + s * 2048);
    const float2* raw2 = reinterpret_cast<const float2*>(tw + s * 2048);

    #pragma unroll
    for (int k = 0; k < 8; ++k) {
        float4 val;
        if (s < 2) {
            const int eh = k >> 1, j = k & 1;
            val = raw4[eh * 128 + lane * 2 + j];
        } else if (s < 8) {
            const int b = s - 2, m = 1 << b;
            const int i = (lane >> b) & 1;
            const int lp = ((lane >> (b + 1)) << b) | (lane & (m - 1));
            const int eh = k >> 1, ep = k & 1;
            // 2x2 row i for the two elements of this k
            float2 a = raw2[(eh * 128 + lp * 4 + 2 * ep) * 2 + i];
            float2 c = raw2[(eh * 128 + lp * 4 + 2 * ep + 1) * 2 + i];
            // bake the i-select: out = val.{x,z}*own + val.{y,w}*partner
            if (i) { a = make_float2(a.y, a.x); c = make_float2(c.y, c.x); }
            val = make_float4(a.x, a.y, c.x, c.y);
        } else {
            const int g = k >> 2, el = k & 3;
            val = raw4[g * 256 + lane * 4 + el];
        }
        ws[(s * 8 + k) * 64 + lane] = val;
    }
}

// ---------------- main kernel (repacked twiddle from global/L1) ------------
__global__ __launch_bounds__(256) void butterfly_kernel(
    const float* __restrict__ x,
    const float4* __restrict__ tws,
    const float* __restrict__ bias,
    float* __restrict__ out)
{
    const int lane = threadIdx.x & 63;
    const int wave_in_block = threadIdx.x >> 6;
    const int gwave = blockIdx.x * 4 + wave_in_block;
    const int row0 = gwave * RPW;

    float v[RPW][4][4];

    const float4* x4 = reinterpret_cast<const float4*>(x);
    #pragma unroll
    for (int q = 0; q < RPW; ++q) {
        #pragma unroll
        for (int eh = 0; eh < 4; ++eh) {
            float4 t = x4[(row0 + q) * 256 + eh * 64 + lane];
            v[q][eh][0] = t.x; v[q][eh][1] = t.y;
            v[q][eh][2] = t.z; v[q][eh][3] = t.w;
        }
    }

    // ---- stage 0: pairs (e_lo 0,1),(2,3)
    #pragma unroll
    for (int k = 0; k < 8; ++k) {
        const float4 T = tws[(0 * 8 + k) * 64 + lane];
        const int eh = k >> 1, j = k & 1;
        #pragma unroll
        for (int q = 0; q < RPW; ++q) {
            const float a = v[q][eh][2 * j];
            const float b = v[q][eh][2 * j + 1];
            v[q][eh][2 * j]     = T.x * a + T.y * b;
            v[q][eh][2 * j + 1] = T.z * a + T.w * b;
        }
    }

    // ---- stage 1: pairs (e_lo 0,2),(1,3)
    #pragma unroll
    for (int k = 0; k < 8; ++k) {
        const float4 T = tws[(1 * 8 + k) * 64 + lane];
        const int eh = k >> 1, j = k & 1;
        #pragma unroll
        for (int q = 0; q < RPW; ++q) {
            const float a = v[q][eh][j];
            const float b = v[q][eh][j + 2];
            v[q][eh][j]     = T.x * a + T.y * b;
            v[q][eh][j + 2] = T.z * a + T.w * b;
        }
    }

    // ---- stages 2..7: partner lane = lane ^ (1 << (s-2)); select pre-baked
    #pragma unroll
    for (int s = 2; s < 8; ++s) {
        const int m = 1 << (s - 2);
        float4 T[8];
        #pragma unroll
        for (int k = 0; k < 8; ++k) T[k] = tws[(s * 8 + k) * 64 + lane];
        #pragma unroll
        for (int q = 0; q < RPW; ++q) {
            #pragma unroll
            for (int k = 0; k < 8; ++k) {
                const int eh = k >> 1, ep = k & 1;
                {
                    const float own = v[q][eh][2 * ep];
                    const float p = __shfl_xor(own, m, 64);
                    v[q][eh][2 * ep] = T[k].x * own + T[k].y * p;
                }
                {
                    const float own = v[q][eh][2 * ep + 1];
                    const float p = __shfl_xor(own, m, 64);
                    v[q][eh][2 * ep + 1] = T[k].z * own + T[k].w * p;
                }
            }
        }
    }

    // ---- stage 8: pairs (e_hi 0,1),(2,3)
    #pragma unroll
    for (int k = 0; k < 8; ++k) {
        const float4 T = tws[(8 * 8 + k) * 64 + lane];
        const int g = k >> 2, el = k & 3;
        #pragma unroll
        for (int q = 0; q < RPW; ++q) {
            const float a = v[q][2 * g][el];
            const float b = v[q][2 * g + 1][el];
            v[q][2 * g][el]     = T.x * a + T.y * b;
            v[q][2 * g + 1][el] = T.z * a + T.w * b;
        }
    }

    // ---- stage 9: pairs (e_hi 0,2),(1,3)
    #pragma unroll
    for (int k = 0; k < 8; ++k) {
        const float4 T = tws[(9 * 8 + k) * 64 + lane];
        const int h = k >> 2, el = k & 3;
        #pragma unroll
        for (int q = 0; q < RPW; ++q) {
            const float a = v[q][h][el];
            const float b = v[q][h + 2][el];
            v[q][h][el]     = T.x * a + T.y * b;
            v[q][h + 2][el] = T.z * a + T.w * b;
        }
    }

    // ---- bias + store
    float4* o4 = reinterpret_cast<float4*>(out);
    const float4* b4 = reinterpret_cast<const float4*>(bias);
    #pragma unroll
    for (int eh = 0; eh < 4; ++eh) {
        const float4 bb = b4[eh * 64 + lane];
        #pragma unroll
        for (int q = 0; q < RPW; ++q) {
            float4 t;
            t.x = v[q][eh][0] + bb.x;
            t.y = v[q][eh][1] + bb.y;
            t.z = v[q][eh][2] + bb.z;
            t.w = v[q][eh][3] + bb.w;
            o4[(row0 + q) * 256 + eh * 64 + lane] = t;
        }
    }
}

// ---------------- fallback (raw twiddle, RPW=2) ----------------------------
__global__ __launch_bounds__(256) void butterfly_fallback(
    const float* __restrict__ x,
    const float* __restrict__ tw,
    const float* __restrict__ bias,
    float* __restrict__ out)
{
    const int lane = threadIdx.x & 63;
    const int wave_in_block = threadIdx.x >> 6;
    const int gwave = blockIdx.x * 4 + wave_in_block;
    const int row0 = gwave * 2;

    float v[2][4][4];
    const float4* x4 = reinterpret_cast<const float4*>(x);
    #pragma unroll
    for (int q = 0; q < 2; ++q)
        #pragma unroll
        for (int eh = 0; eh < 4; ++eh) {
            float4 t = x4[(row0 + q) * 256 + eh * 64 + lane];
            v[q][eh][0] = t.x; v[q][eh][1] = t.y;
            v[q][eh][2] = t.z; v[q][eh][3] = t.w;
        }

    #pragma unroll
    for (int s = 0; s < 2; ++s) {
        const float4* t4 = reinterpret_cast<const float4*>(tw + s * 2048);
        #pragma unroll
        for (int eh = 0; eh < 4; ++eh)
            #pragma unroll
            for (int j = 0; j < 2; ++j) {
                const float4 T = t4[eh * 128 + lane * 2 + j];
                #pragma unroll
                for (int q = 0; q < 2; ++q) {
                    const int a0 = (s == 0) ? 2 * j : j;
                    const int a1 = (s == 0) ? 2 * j + 1 : j + 2;
                    const float a = v[q][eh][a0];
                    const float b = v[q][eh][a1];
                    v[q][eh][a0] = T.x * a + T.y * b;
                    v[q][eh][a1] = T.z * a + T.w * b;
                }
            }
    }
    #pragma unroll
    for (int s = 2; s < 8; ++s) {
        const int b = s - 2, m = 1 << b;
        const int i = (lane >> b) & 1;
        const int lp = ((lane >> (b + 1)) << b) | (lane & (m - 1));
        const float2* t2 = reinterpret_cast<const float2*>(tw + s * 2048);
        float2 T[4][4];
        #pragma unroll
        for (int eh = 0; eh < 4; ++eh)
            #pragma unroll
            for (int el = 0; el < 4; ++el)
                T[eh][el] = t2[(eh * 128 + lp * 4 + el) * 2 + i];
        #pragma unroll
        for (int q = 0; q < 2; ++q)
            #pragma unroll
            for (int eh = 0; eh < 4; ++eh)
                #pragma unroll
                for (int el = 0; el < 4; ++el) {
                    const float own = v[q][eh][el];
                    const float p = __shfl_xor(own, m, 64);
                    const float x0 = i ? p : own;
                    const float x1 = i ? own : p;
                    v[q][eh][el] = T[eh][el].x * x0 + T[eh][el].y * x1;
                }
    }
    #pragma unroll
    for (int s = 8; s < 10; ++s) {
        const float4* t4 = reinterpret_cast<const float4*>(tw + s * 2048);
        #pragma unroll
        for (int g = 0; g < 2; ++g)
            #pragma unroll
            for (int el = 0; el < 4; ++el) {
                const float4 T = t4[g * 256 + lane * 4 + el];
                #pragma unroll
                for (int q = 0; q < 2; ++q) {
                    const int a0 = (s == 8) ? 2 * g : g;
                    const int a1 = (s == 8) ? 2 * g + 1 : g + 2;
                    const float a = v[q][a0][el];
                    const float b = v[q][a1][el];
                    v[q][a0][el] = T.x * a + T.y * b;
                    v[q][a1][el] = T.z * a + T.w * b;
                }
            }
    }
    float4* o4 = reinterpret_cast<float4*>(out);
    const float4* b4 = reinterpret_cast<const float4*>(bias);
    #pragma unroll
    for (int eh = 0; eh < 4; ++eh) {
        const float4 bb = b4[eh * 64 + lane];
        #pragma unroll
        for (int q = 0; q < 2; ++q) {
            float4 t;
            t.x = v[q][eh][0] + bb.x;
            t.y = v[q][eh][1] + bb.y;
            t.z = v[q][eh][2] + bb.z;
            t.w = v[q][eh][3] + bb.w;
            o4[(row0 + q) * 256 + eh * 64 + lane] = t;
        }
    }
}

extern "C" void kernel_launch(void* const* d_in, const int* in_sizes, int n_in,
                              void* d_out, int out_size, void* d_ws, size_t ws_size,
                              hipStream_t stream) {
    const float* x    = (const float*)d_in[0];  // (16384, 1024)
    const float* tw   = (const float*)d_in[1];  // (1, 10, 512, 2, 2)
    const float* bias = (const float*)d_in[2];  // (1024,)
    float* out = (float*)d_out;

    if (ws_size >= TWS_BYTES) {
        float4* tws = (float4*)d_ws;
        repack_tw<<<10, 64, 0, stream>>>(tw, tws);
        const int blocks = (BATCH / RPW) / 4;   // 2048
        butterfly_kernel<<<blocks, 256, 0, stream>>>(x, tws, bias, out);
    } else {
        const int blocks = (BATCH / 2) / 4;     // 2048
        butterfly_fallback<<<blocks, 256, 0, stream>>>(x, tw, bias, out);
    }
}

// Round 12
// 48.125 us; speedup vs baseline: 1.2418x; 1.2418x over previous
//
#include <hip/hip_runtime.h>

// Butterfly (untied, increasing stride): BATCH=16384, N=1024, M=10, NSTACK=1.
// out = butterfly_mult(twiddle, x) + bias, all float32.
//
// Layout: pos = e_hi*256 + lane*4 + e_lo  (e_hi, e_lo in 0..3).
//   - stages 0..1: in-register pairs over e_lo bits.
//   - stages 2..7: cross-lane __shfl_xor over lane bits.
//   - stages 8..9: in-register pairs over e_hi bits.
//
// v12 = v5 (proven 43us: repacked twiddle via global/L1, cndmask selects)
//     with RPW 2 -> 4. Diagnosis: dominant stall is twiddle L2 latency
//     (each wave re-reads 80KB; 640MB L2 traffic total; v11 cut VALU work
//     and got SLOWER -> latency- not issue-bound). RPW=4 halves per-row
//     twiddle reads and doubles dependent work per load.
//     RPW=4 needs ~140 VGPR (v1/v2 measured 132/140, no spill) so the
//     128-VGPR cap launch_bounds(256,4) is replaced by (256,2) -- cap 256,
//     no squeeze. Session spill lessons: no tight caps (v4/v6/v7/v8),
//     no sweep loop / LICM bait (v8).
//     Spill canary: WRITE_SIZE must stay ~65-67 MB.

#define BATCH 16384
#define NCOL 1024
#define RPW 4
#define TWS_BYTES (10 * 8 * 64 * 16)  // 81920

// ---------------- repack kernel: blockIdx.x = stage, threadIdx.x = lane ----
__global__ __launch_bounds__(64) void repack_tw(
    const float* __restrict__ tw, float4* __restrict__ ws)
{
    const int s = blockIdx.x;
    const int lane = threadIdx.x;
    const float4* raw4 = reinterpret_cast<const float4*>(tw + s * 2048);
    const float2* raw2 = reinterpret_cast<const float2*>(tw + s * 2048);

    #pragma unroll
    for (int k = 0; k < 8; ++k) {
        float4 val;
        if (s < 2) {
            const int eh = k >> 1, j = k & 1;
            val = raw4[eh * 128 + lane * 2 + j];
        } else if (s < 8) {
            const int b = s - 2, m = 1 << b;
            const int i = (lane >> b) & 1;
            const int lp = ((lane >> (b + 1)) << b) | (lane & (m - 1));
            const int eh = k >> 1, ep = k & 1;
            float2 a = raw2[(eh * 128 + lp * 4 + 2 * ep) * 2 + i];
            float2 c = raw2[(eh * 128 + lp * 4 + 2 * ep + 1) * 2 + i];
            val = make_float4(a.x, a.y, c.x, c.y);
        } else {
            const int g = k >> 2, el = k & 3;
            val = raw4[g * 256 + lane * 4 + el];
        }
        ws[(s * 8 + k) * 64 + lane] = val;
    }
}

// ---------------- main kernel (repacked twiddle, RPW=4) --------------------
__global__ __launch_bounds__(256, 2) void butterfly_kernel(
    const float* __restrict__ x,
    const float4* __restrict__ tws,
    const float* __restrict__ bias,
    float* __restrict__ out)
{
    const int lane = threadIdx.x & 63;
    const int wave_in_block = threadIdx.x >> 6;
    const int gwave = blockIdx.x * 4 + wave_in_block;
    const int row0 = gwave * RPW;

    float v[RPW][4][4];

    const float4* x4 = reinterpret_cast<const float4*>(x);
    #pragma unroll
    for (int q = 0; q < RPW; ++q) {
        #pragma unroll
        for (int eh = 0; eh < 4; ++eh) {
            float4 t = x4[(row0 + q) * 256 + eh * 64 + lane];
            v[q][eh][0] = t.x; v[q][eh][1] = t.y;
            v[q][eh][2] = t.z; v[q][eh][3] = t.w;
        }
    }

    // ---- stage 0: pairs (e_lo 0,1),(2,3)
    #pragma unroll
    for (int k = 0; k < 8; ++k) {
        const float4 T = tws[(0 * 8 + k) * 64 + lane];
        const int eh = k >> 1, j = k & 1;
        #pragma unroll
        for (int q = 0; q < RPW; ++q) {
            const float a = v[q][eh][2 * j];
            const float b = v[q][eh][2 * j + 1];
            v[q][eh][2 * j]     = T.x * a + T.y * b;
            v[q][eh][2 * j + 1] = T.z * a + T.w * b;
        }
    }

    // ---- stage 1: pairs (e_lo 0,2),(1,3)
    #pragma unroll
    for (int k = 0; k < 8; ++k) {
        const float4 T = tws[(1 * 8 + k) * 64 + lane];
        const int eh = k >> 1, j = k & 1;
        #pragma unroll
        for (int q = 0; q < RPW; ++q) {
            const float a = v[q][eh][j];
            const float b = v[q][eh][j + 2];
            v[q][eh][j]     = T.x * a + T.y * b;
            v[q][eh][j + 2] = T.z * a + T.w * b;
        }
    }

    // ---- stages 2..7: partner lane = lane ^ (1 << (s-2))
    #pragma unroll
    for (int s = 2; s < 8; ++s) {
        const int b = s - 2;
        const int m = 1 << b;
        const int i = (lane >> b) & 1;   // bit s of pos
        float4 T[8];
        #pragma unroll
        for (int k = 0; k < 8; ++k) T[k] = tws[(s * 8 + k) * 64 + lane];
        #pragma unroll
        for (int q = 0; q < RPW; ++q) {
            #pragma unroll
            for (int k = 0; k < 8; ++k) {
                const int eh = k >> 1, ep = k & 1;
                {
                    const float own = v[q][eh][2 * ep];
                    const float p = __shfl_xor(own, m, 64);
                    const float x0 = i ? p : own;
                    const float x1 = i ? own : p;
                    v[q][eh][2 * ep] = T[k].x * x0 + T[k].y * x1;
                }
                {
                    const float own = v[q][eh][2 * ep + 1];
                    const float p = __shfl_xor(own, m, 64);
                    const float x0 = i ? p : own;
                    const float x1 = i ? own : p;
                    v[q][eh][2 * ep + 1] = T[k].z * x0 + T[k].w * x1;
                }
            }
        }
    }

    // ---- stage 8: pairs (e_hi 0,1),(2,3)
    #pragma unroll
    for (int k = 0; k < 8; ++k) {
        const float4 T = tws[(8 * 8 + k) * 64 + lane];
        const int g = k >> 2, el = k & 3;
        #pragma unroll
        for (int q = 0; q < RPW; ++q) {
            const float a = v[q][2 * g][el];
            const float b = v[q][2 * g + 1][el];
            v[q][2 * g][el]     = T.x * a + T.y * b;
            v[q][2 * g + 1][el] = T.z * a + T.w * b;
        }
    }

    // ---- stage 9: pairs (e_hi 0,2),(1,3)
    #pragma unroll
    for (int k = 0; k < 8; ++k) {
        const float4 T = tws[(9 * 8 + k) * 64 + lane];
        const int h = k >> 2, el = k & 3;
        #pragma unroll
        for (int q = 0; q < RPW; ++q) {
            const float a = v[q][h][el];
            const float b = v[q][h + 2][el];
            v[q][h][el]     = T.x * a + T.y * b;
            v[q][h + 2][el] = T.z * a + T.w * b;
        }
    }

    // ---- bias + store
    float4* o4 = reinterpret_cast<float4*>(out);
    const float4* b4 = reinterpret_cast<const float4*>(bias);
    #pragma unroll
    for (int eh = 0; eh < 4; ++eh) {
        const float4 bb = b4[eh * 64 + lane];
        #pragma unroll
        for (int q = 0; q < RPW; ++q) {
            float4 t;
            t.x = v[q][eh][0] + bb.x;
            t.y = v[q][eh][1] + bb.y;
            t.z = v[q][eh][2] + bb.z;
            t.w = v[q][eh][3] + bb.w;
            o4[(row0 + q) * 256 + eh * 64 + lane] = t;
        }
    }
}

// ---------------- fallback (raw twiddle, RPW=2) ----------------------------
__global__ __launch_bounds__(256) void butterfly_fallback(
    const float* __restrict__ x,
    const float* __restrict__ tw,
    const float* __restrict__ bias,
    float* __restrict__ out)
{
    const int lane = threadIdx.x & 63;
    const int wave_in_block = threadIdx.x >> 6;
    const int gwave = blockIdx.x * 4 + wave_in_block;
    const int row0 = gwave * 2;

    float v[2][4][4];
    const float4* x4 = reinterpret_cast<const float4*>(x);
    #pragma unroll
    for (int q = 0; q < 2; ++q)
        #pragma unroll
        for (int eh = 0; eh < 4; ++eh) {
            float4 t = x4[(row0 + q) * 256 + eh * 64 + lane];
            v[q][eh][0] = t.x; v[q][eh][1] = t.y;
            v[q][eh][2] = t.z; v[q][eh][3] = t.w;
        }

    #pragma unroll
    for (int s = 0; s < 2; ++s) {
        const float4* t4 = reinterpret_cast<const float4*>(tw + s * 2048);
        #pragma unroll
        for (int eh = 0; eh < 4; ++eh)
            #pragma unroll
            for (int j = 0; j < 2; ++j) {
                const float4 T = t4[eh * 128 + lane * 2 + j];
                #pragma unroll
                for (int q = 0; q < 2; ++q) {
                    const int a0 = (s == 0) ? 2 * j : j;
                    const int a1 = (s == 0) ? 2 * j + 1 : j + 2;
                    const float a = v[q][eh][a0];
                    const float b = v[q][eh][a1];
                    v[q][eh][a0] = T.x * a + T.y * b;
                    v[q][eh][a1] = T.z * a + T.w * b;
                }
            }
    }
    #pragma unroll
    for (int s = 2; s < 8; ++s) {
        const int b = s - 2, m = 1 << b;
        const int i = (lane >> b) & 1;
        const int lp = ((lane >> (b + 1)) << b) | (lane & (m - 1));
        const float2* t2 = reinterpret_cast<const float2*>(tw + s * 2048);
        float2 T[4][4];
        #pragma unroll
        for (int eh = 0; eh < 4; ++eh)
            #pragma unroll
            for (int el = 0; el < 4; ++el)
                T[eh][el] = t2[(eh * 128 + lp * 4 + el) * 2 + i];
        #pragma unroll
        for (int q = 0; q < 2; ++q)
            #pragma unroll
            for (int eh = 0; eh < 4; ++eh)
                #pragma unroll
                for (int el = 0; el < 4; ++el) {
                    const float own = v[q][eh][el];
                    const float p = __shfl_xor(own, m, 64);
                    const float x0 = i ? p : own;
                    const float x1 = i ? own : p;
                    v[q][eh][el] = T[eh][el].x * x0 + T[eh][el].y * x1;
                }
    }
    #pragma unroll
    for (int s = 8; s < 10; ++s) {
        const float4* t4 = reinterpret_cast<const float4*>(tw + s * 2048);
        #pragma unroll
        for (int g = 0; g < 2; ++g)
            #pragma unroll
            for (int el = 0; el < 4; ++el) {
                const float4 T = t4[g * 256 + lane * 4 + el];
                #pragma unroll
                for (int q = 0; q < 2; ++q) {
                    const int a0 = (s == 8) ? 2 * g : g;
                    const int a1 = (s == 8) ? 2 * g + 1 : g + 2;
                    const float a = v[q][a0][el];
                    const float b = v[q][a1][el];
                    v[q][a0][el] = T.x * a + T.y * b;
                    v[q][a1][el] = T.z * a + T.w * b;
                }
            }
    }
    float4* o4 = reinterpret_cast<float4*>(out);
    const float4* b4 = reinterpret_cast<const float4*>(bias);
    #pragma unroll
    for (int eh = 0; eh < 4; ++eh) {
        const float4 bb = b4[eh * 64 + lane];
        #pragma unroll
        for (int q = 0; q < 2; ++q) {
            float4 t;
            t.x = v[q][eh][0] + bb.x;
            t.y = v[q][eh][1] + bb.y;
            t.z = v[q][eh][2] + bb.z;
            t.w = v[q][eh][3] + bb.w;
            o4[(row0 + q) * 256 + eh * 64 + lane] = t;
        }
    }
}

extern "C" void kernel_launch(void* const* d_in, const int* in_sizes, int n_in,
                              void* d_out, int out_size, void* d_ws, size_t ws_size,
                              hipStream_t stream) {
    const float* x    = (const float*)d_in[0];  // (16384, 1024)
    const float* tw   = (const float*)d_in[1];  // (1, 10, 512, 2, 2)
    const float* bias = (const float*)d_in[2];  // (1024,)
    float* out = (float*)d_out;

    if (ws_size >= TWS_BYTES) {
        float4* tws = (float4*)d_ws;
        repack_tw<<<10, 64, 0, stream>>>(tw, tws);
        const int blocks = (BATCH / RPW) / 4;   // 1024
        butterfly_kernel<<<blocks, 256, 0, stream>>>(x, tws, bias, out);
    } else {
        const int blocks = (BATCH / 2) / 4;     // 2048
        butterfly_fallback<<<blocks, 256, 0, stream>>>(x, tw, bias, out);
    }
}

// Round 13
// 43.863 us; speedup vs baseline: 1.3624x; 1.0972x over previous
//
#include <hip/hip_runtime.h>

// Butterfly (untied, increasing stride): BATCH=16384, N=1024, M=10, NSTACK=1.
// out = butterfly_mult(twiddle, x) + bias, all float32.
//
// Layout: pos = e_hi*256 + lane*4 + e_lo  (e_hi, e_lo in 0..3).
//   - stages 0..1: in-register pairs over e_lo bits.
//   - stages 2..7: cross-lane over lane bits (masks 1,2,4,8,16,32).
//   - stages 8..9: in-register pairs over e_hi bits.
//
// v13 = v5 (best measured: 43us; repacked twiddle via global/L1, cndmask
//     selects, RPW=2) with ONE change: the xor-1 / xor-2 / xor-8 lane
//     exchanges use DPP (quad_perm 0xB1 / 0x4E, row_ror:8 = 0x128) on the
//     VALU pipe instead of __shfl_xor on the DS pipe. DS ops per wave
//     192 -> 96; device DS-pipe demand ~15us -> ~8us. The DS pipe was the
//     largest compute-pipe demand and sits in every stage's dep chain.
//     Masks 4,16,32 keep __shfl_xor (no DPP encoding for those).
//     Session lessons kept: no tight launch_bounds caps (v4/v6/v7/v8
//     spills), no sweep loop (v8 LICM spill), RPW=2 (RPW=4 ~140 VGPR),
//     unbaked twiddle (v11's baked swap regressed).
//     Spill canary: WRITE_SIZE must stay ~65-67 MB.

#define BATCH 16384
#define NCOL 1024
#define RPW 2
#define TWS_BYTES (10 * 8 * 64 * 16)  // 81920

// ---- DPP cross-lane: out[l] = in[l ^ M] for M in {1,2,8} ------------------
template<int CTRL>
__device__ __forceinline__ float fdpp(float x) {
    int xi = __builtin_bit_cast(int, x);
    int r = __builtin_amdgcn_update_dpp(0, xi, CTRL, 0xf, 0xf, false);
    return __builtin_bit_cast(float, r);
}

template<int M>
__device__ __forceinline__ float xpartner(float x) {
    if constexpr (M == 1)       return fdpp<0xB1>(x);   // quad_perm [1,0,3,2]
    else if constexpr (M == 2)  return fdpp<0x4E>(x);   // quad_perm [2,3,0,1]
    else if constexpr (M == 8)  return fdpp<0x128>(x);  // row_ror:8 (== xor 8)
    else                        return __shfl_xor(x, M, 64);
}

// ---------------- repack kernel: blockIdx.x = stage, threadIdx.x = lane ----
__global__ __launch_bounds__(64) void repack_tw(
    const float* __restrict__ tw, float4* __restrict__ ws)
{
    const int s = blockIdx.x;
    const int lane = threadIdx.x;
    const float4* raw4 = reinterpret_cast<const float4*>(tw + s * 2048);
    const float2* raw2 = reinterpret_cast<const float2*>(tw + s * 2048);

    #pragma unroll
    for (int k = 0; k < 8; ++k) {
        float4 val;
        if (s < 2) {
            const int eh = k >> 1, j = k & 1;
            val = raw4[eh * 128 + lane * 2 + j];
        } else if (s < 8) {
            const int b = s - 2, m = 1 << b;
            const int i = (lane >> b) & 1;
            const int lp = ((lane >> (b + 1)) << b) | (lane & (m - 1));
            const int eh = k >> 1, ep = k & 1;
            float2 a = raw2[(eh * 128 + lp * 4 + 2 * ep) * 2 + i];
            float2 c = raw2[(eh * 128 + lp * 4 + 2 * ep + 1) * 2 + i];
            val = make_float4(a.x, a.y, c.x, c.y);
        } else {
            const int g = k >> 2, el = k & 3;
            val = raw4[g * 256 + lane * 4 + el];
        }
        ws[(s * 8 + k) * 64 + lane] = val;
    }
}

// ---- one cross-lane stage (S in 2..7), twiddle from tws -------------------
template<int S>
__device__ __forceinline__ void shfl_stage(
    float v[RPW][4][4], const float4* __restrict__ tws, int lane)
{
    constexpr int b = S - 2;
    constexpr int m = 1 << b;
    const int i = (lane >> b) & 1;   // bit S of pos
    float4 T[8];
    #pragma unroll
    for (int k = 0; k < 8; ++k) T[k] = tws[(S * 8 + k) * 64 + lane];
    #pragma unroll
    for (int q = 0; q < RPW; ++q) {
        #pragma unroll
        for (int k = 0; k < 8; ++k) {
            const int eh = k >> 1, ep = k & 1;
            {
                const float own = v[q][eh][2 * ep];
                const float p = xpartner<m>(own);
                const float x0 = i ? p : own;
                const float x1 = i ? own : p;
                v[q][eh][2 * ep] = T[k].x * x0 + T[k].y * x1;
            }
            {
                const float own = v[q][eh][2 * ep + 1];
                const float p = xpartner<m>(own);
                const float x0 = i ? p : own;
                const float x1 = i ? own : p;
                v[q][eh][2 * ep + 1] = T[k].z * x0 + T[k].w * x1;
            }
        }
    }
}

// ---------------- main kernel (repacked twiddle from global/L1) ------------
__global__ __launch_bounds__(256) void butterfly_kernel(
    const float* __restrict__ x,
    const float4* __restrict__ tws,
    const float* __restrict__ bias,
    float* __restrict__ out)
{
    const int lane = threadIdx.x & 63;
    const int wave_in_block = threadIdx.x >> 6;
    const int gwave = blockIdx.x * 4 + wave_in_block;
    const int row0 = gwave * RPW;

    float v[RPW][4][4];

    const float4* x4 = reinterpret_cast<const float4*>(x);
    #pragma unroll
    for (int q = 0; q < RPW; ++q) {
        #pragma unroll
        for (int eh = 0; eh < 4; ++eh) {
            float4 t = x4[(row0 + q) * 256 + eh * 64 + lane];
            v[q][eh][0] = t.x; v[q][eh][1] = t.y;
            v[q][eh][2] = t.z; v[q][eh][3] = t.w;
        }
    }

    // ---- stage 0: pairs (e_lo 0,1),(2,3)
    #pragma unroll
    for (int k = 0; k < 8; ++k) {
        const float4 T = tws[(0 * 8 + k) * 64 + lane];
        const int eh = k >> 1, j = k & 1;
        #pragma unroll
        for (int q = 0; q < RPW; ++q) {
            const float a = v[q][eh][2 * j];
            const float b = v[q][eh][2 * j + 1];
            v[q][eh][2 * j]     = T.x * a + T.y * b;
            v[q][eh][2 * j + 1] = T.z * a + T.w * b;
        }
    }

    // ---- stage 1: pairs (e_lo 0,2),(1,3)
    #pragma unroll
    for (int k = 0; k < 8; ++k) {
        const float4 T = tws[(1 * 8 + k) * 64 + lane];
        const int eh = k >> 1, j = k & 1;
        #pragma unroll
        for (int q = 0; q < RPW; ++q) {
            const float a = v[q][eh][j];
            const float b = v[q][eh][j + 2];
            v[q][eh][j]     = T.x * a + T.y * b;
            v[q][eh][j + 2] = T.z * a + T.w * b;
        }
    }

    // ---- stages 2..7: cross-lane (DPP for m=1,2,8; shfl for m=4,16,32)
    shfl_stage<2>(v, tws, lane);
    shfl_stage<3>(v, tws, lane);
    shfl_stage<4>(v, tws, lane);
    shfl_stage<5>(v, tws, lane);
    shfl_stage<6>(v, tws, lane);
    shfl_stage<7>(v, tws, lane);

    // ---- stage 8: pairs (e_hi 0,1),(2,3)
    #pragma unroll
    for (int k = 0; k < 8; ++k) {
        const float4 T = tws[(8 * 8 + k) * 64 + lane];
        const int g = k >> 2, el = k & 3;
        #pragma unroll
        for (int q = 0; q < RPW; ++q) {
            const float a = v[q][2 * g][el];
            const float b = v[q][2 * g + 1][el];
            v[q][2 * g][el]     = T.x * a + T.y * b;
            v[q][2 * g + 1][el] = T.z * a + T.w * b;
        }
    }

    // ---- stage 9: pairs (e_hi 0,2),(1,3)
    #pragma unroll
    for (int k = 0; k < 8; ++k) {
        const float4 T = tws[(9 * 8 + k) * 64 + lane];
        const int h = k >> 2, el = k & 3;
        #pragma unroll
        for (int q = 0; q < RPW; ++q) {
            const float a = v[q][h][el];
            const float b = v[q][h + 2][el];
            v[q][h][el]     = T.x * a + T.y * b;
            v[q][h + 2][el] = T.z * a + T.w * b;
        }
    }

    // ---- bias + store
    float4* o4 = reinterpret_cast<float4*>(out);
    const float4* b4 = reinterpret_cast<const float4*>(bias);
    #pragma unroll
    for (int eh = 0; eh < 4; ++eh) {
        const float4 bb = b4[eh * 64 + lane];
        #pragma unroll
        for (int q = 0; q < RPW; ++q) {
            float4 t;
            t.x = v[q][eh][0] + bb.x;
            t.y = v[q][eh][1] + bb.y;
            t.z = v[q][eh][2] + bb.z;
            t.w = v[q][eh][3] + bb.w;
            o4[(row0 + q) * 256 + eh * 64 + lane] = t;
        }
    }
}

// ---------------- fallback (raw twiddle, RPW=2) ----------------------------
__global__ __launch_bounds__(256) void butterfly_fallback(
    const float* __restrict__ x,
    const float* __restrict__ tw,
    const float* __restrict__ bias,
    float* __restrict__ out)
{
    const int lane = threadIdx.x & 63;
    const int wave_in_block = threadIdx.x >> 6;
    const int gwave = blockIdx.x * 4 + wave_in_block;
    const int row0 = gwave * 2;

    float v[2][4][4];
    const float4* x4 = reinterpret_cast<const float4*>(x);
    #pragma unroll
    for (int q = 0; q < 2; ++q)
        #pragma unroll
        for (int eh = 0; eh < 4; ++eh) {
            float4 t = x4[(row0 + q) * 256 + eh * 64 + lane];
            v[q][eh][0] = t.x; v[q][eh][1] = t.y;
            v[q][eh][2] = t.z; v[q][eh][3] = t.w;
        }

    #pragma unroll
    for (int s = 0; s < 2; ++s) {
        const float4* t4 = reinterpret_cast<const float4*>(tw + s * 2048);
        #pragma unroll
        for (int eh = 0; eh < 4; ++eh)
            #pragma unroll
            for (int j = 0; j < 2; ++j) {
                const float4 T = t4[eh * 128 + lane * 2 + j];
                #pragma unroll
                for (int q = 0; q < 2; ++q) {
                    const int a0 = (s == 0) ? 2 * j : j;
                    const int a1 = (s == 0) ? 2 * j + 1 : j + 2;
                    const float a = v[q][eh][a0];
                    const float b = v[q][eh][a1];
                    v[q][eh][a0] = T.x * a + T.y * b;
                    v[q][eh][a1] = T.z * a + T.w * b;
                }
            }
    }
    #pragma unroll
    for (int s = 2; s < 8; ++s) {
        const int b = s - 2, m = 1 << b;
        const int i = (lane >> b) & 1;
        const int lp = ((lane >> (b + 1)) << b) | (lane & (m - 1));
        const float2* t2 = reinterpret_cast<const float2*>(tw + s * 2048);
        float2 T[4][4];
        #pragma unroll
        for (int eh = 0; eh < 4; ++eh)
            #pragma unroll
            for (int el = 0; el < 4; ++el)
                T[eh][el] = t2[(eh * 128 + lp * 4 + el) * 2 + i];
        #pragma unroll
        for (int q = 0; q < 2; ++q)
            #pragma unroll
            for (int eh = 0; eh < 4; ++eh)
                #pragma unroll
                for (int el = 0; el < 4; ++el) {
                    const float own = v[q][eh][el];
                    const float p = __shfl_xor(own, m, 64);
                    const float x0 = i ? p : own;
                    const float x1 = i ? own : p;
                    v[q][eh][el] = T[eh][el].x * x0 + T[eh][el].y * x1;
                }
    }
    #pragma unroll
    for (int s = 8; s < 10; ++s) {
        const float4* t4 = reinterpret_cast<const float4*>(tw + s * 2048);
        #pragma unroll
        for (int g = 0; g < 2; ++g)
            #pragma unroll
            for (int el = 0; el < 4; ++el) {
                const float4 T = t4[g * 256 + lane * 4 + el];
                #pragma unroll
                for (int q = 0; q < 2; ++q) {
                    const int a0 = (s == 8) ? 2 * g : g;
                    const int a1 = (s == 8) ? 2 * g + 1 : g + 2;
                    const float a = v[q][a0][el];
                    const float b = v[q][a1][el];
                    v[q][a0][el] = T.x * a + T.y * b;
                    v[q][a1][el] = T.z * a + T.w * b;
                }
            }
    }
    float4* o4 = reinterpret_cast<float4*>(out);
    const float4* b4 = reinterpret_cast<const float4*>(bias);
    #pragma unroll
    for (int eh = 0; eh < 4; ++eh) {
        const float4 bb = b4[eh * 64 + lane];
        #pragma unroll
        for (int q = 0; q < 2; ++q) {
            float4 t;
            t.x = v[q][eh][0] + bb.x;
            t.y = v[q][eh][1] + bb.y;
            t.z = v[q][eh][2] + bb.z;
            t.w = v[q][eh][3] + bb.w;
            o4[(row0 + q) * 256 + eh * 64 + lane] = t;
        }
    }
}

extern "C" void kernel_launch(void* const* d_in, const int* in_sizes, int n_in,
                              void* d_out, int out_size, void* d_ws, size_t ws_size,
                              hipStream_t stream) {
    const float* x    = (const float*)d_in[0];  // (16384, 1024)
    const float* tw   = (const float*)d_in[1];  // (1, 10, 512, 2, 2)
    const float* bias = (const float*)d_in[2];  // (1024,)
    float* out = (float*)d_out;

    if (ws_size >= TWS_BYTES) {
        float4* tws = (float4*)d_ws;
        repack_tw<<<10, 64, 0, stream>>>(tw, tws);
        const int blocks = (BATCH / RPW) / 4;   // 2048
        butterfly_kernel<<<blocks, 256, 0, stream>>>(x, tws, bias, out);
    } else {
        const int blocks = (BATCH / 2) / 4;     // 2048
        butterfly_fallback<<<blocks, 256, 0, stream>>>(x, tw, bias, out);
    }
}